// Round 18
// baseline (53.073 us; speedup 1.0000x reference)
//
#include <hip/hip_runtime.h>
#include <stdint.h>

typedef short bf16x8 __attribute__((ext_vector_type(8)));
typedef float f32x4 __attribute__((ext_vector_type(4)));
typedef float f32x16 __attribute__((ext_vector_type(16)));

#define NCI 128
#define NCO 128
#define HIN 64
#define NB  8

__device__ __forceinline__ unsigned short f32_to_bf16(float f) {
    union { float f; uint32_t u; } v; v.f = f;
    return (unsigned short)((v.u + 0x7FFFu + ((v.u >> 16) & 1u)) >> 16);
}

// Effective 2x2-tap weight for parity (py,px), tap (ty,tx)
__device__ __forceinline__ float weff_sum(const float* wp, int py, int px, int ty, int tx) {
    float s = 0.f;
    #pragma unroll
    for (int ky = 0; ky < 3; ++ky) {
        bool iy = (py == 0) ? (ty == 0 ? (ky == 0) : (ky >= 1))
                            : (ty == 0 ? (ky <= 1) : (ky == 2));
        if (!iy) continue;
        #pragma unroll
        for (int kx = 0; kx < 3; ++kx) {
            bool ix = (px == 0) ? (tx == 0 ? (kx == 0) : (kx >= 1))
                                : (tx == 0 ? (kx <= 1) : (kx == 2));
            if (ix) s += wp[ky * 3 + kx];
        }
    }
    return s;
}

// Weff -> Aw9 (1KB wave-line frags for 32x32x16), layout unchanged from r16:
//   offset = (((par*2+coh)*32 + s)*1024) + fm*512 + lane*8 + e
//   content = Weff[par][co = coh*64 + fm*32 + (lane&31)][k = s*16 + (lane>>5)*8 + e]
__global__ __launch_bounds__(256) void weff9_kernel(
        const float* __restrict__ W, unsigned short* __restrict__ Aw9) {
    int idx = blockIdx.x * 256 + threadIdx.x;     // 262144 total
    int e   = idx & 7;
    int l   = (idx >> 3) & 63;
    int fm  = (idx >> 9) & 1;
    int s   = (idx >> 10) & 31;
    int coh = (idx >> 15) & 1;
    int par = idx >> 16;
    int co = coh * 64 + fm * 32 + (l & 31);
    int k  = s * 16 + (l >> 5) * 8 + e;
    int tap = k >> 7, ci = k & 127;
    Aw9[idx] = f32_to_bf16(weff_sum(W + (co * NCI + ci) * 9,
                                    par >> 1, par & 1, tap >> 1, tap & 1));
}

// Fused GEMM (r16 structure, xq eliminated): B window (5 rows x 64 cols x
// 256B = 80 KB) staged DIRECTLY from x (f32->bf16, lane = column, L2-local
// image per XCD); A streams L2->reg 3-deep. Block = (bi, py, px, coh, ys);
// 256 thr = 4 waves (ol = oy row); wave = 64co x 64sp, 32 steps x
// {2 A-reads, 2 B-reads (halo-select), 4 MFMA 32x32x16}. 2 blocks/CU.
__global__ __launch_bounds__(256, 2) void upconv19_kernel(
        const float* __restrict__ x, const unsigned short* __restrict__ Aw9,
        const float* __restrict__ bv, float* __restrict__ out) {
    __shared__ __align__(16) unsigned short B_lds[40960];   // 81920 B
    const int d = blockIdx.x;                 // 1024 blocks
    const int bi  = d & 7;                    // XCD-local image (x L2-resident)
    const int py  = (d >> 3) & 1;
    const int px  = (d >> 4) & 1;             // partner d^16 on same XCD
    const int coh = (d >> 5) & 1;
    const int ys  = d >> 6;                   // 0..15
    const int tid = threadIdx.x, lane = tid & 63, wv = tid >> 6, ol = wv;
    const int l31 = lane & 31, lh = lane >> 5;
    const int par = py * 2 + px;

    // ---- A prologue first (independent of LDS; overlaps staging) ----
    const unsigned short* Ag = Aw9 + (((size_t)(par * 2 + coh)) << 15);
    bf16x8 Abuf[3][2];
    #pragma unroll
    for (int i = 0; i < 3; ++i) {
        const unsigned short* p = Ag + (i << 10) + lane * 8;
        Abuf[i][0] = *(const bf16x8*)p;
        Abuf[i][1] = *(const bf16x8*)(p + 512);
    }

    // ---- stage B window directly from x: 80 tasks (r 0..4, octet o 0..15),
    //      lane = column w; store octet o at slot ((r*64+w)*16 + (o^(w&15)))
    //      (same slot/swizzle contract as the K-loop reader). ----
    #pragma unroll
    for (int i = 0; i < 20; ++i) {
        const int tk = i * 4 + wv;            // wave-interleaved 0..79
        const int r = tk >> 4, o = tk & 15;
        const int grow = ys * 4 + py + r - 1;
        const bool ok = (unsigned)grow < 64u;
        const float* xp = x + ((size_t)(bi * NCI + o * 8) * HIN + (ok ? grow : 0)) * HIN + lane;
        bf16x8 v;
        #pragma unroll
        for (int j = 0; j < 8; ++j) {
            float f = ok ? xp[(size_t)j * (HIN * HIN)] : 0.f;
            v[j] = (short)f32_to_bf16(f);
        }
        const int w = lane;
        *(bf16x8*)&B_lds[(((r << 6) + w) * 16 + (o ^ (w & 15))) * 8] = v;
    }
    __syncthreads();

    f32x16 acc[2][2];
    #pragma unroll
    for (int i = 0; i < 2; ++i)
        #pragma unroll
        for (int j = 0; j < 2; ++j)
            #pragma unroll
            for (int q = 0; q < 16; ++q)
                acc[i][j][q] = 0.f;

    #pragma unroll
    for (int s = 0; s < 32; ++s) {            // fully unrolled: s%3 static
        bf16x8* Ac = Abuf[s % 3];
        const int ty = s >> 4, tx = (s >> 3) & 1;
        const int q = (s & 7) * 2 + lh;
        const int r = ol + ty;                // 0..4
        __builtin_amdgcn_s_setprio(1);
        #pragma unroll
        for (int fn = 0; fn < 2; ++fn) {
            const int wr = fn * 32 + l31 + px + tx - 1;
            const bool valid = (unsigned)wr < 64u;
            const int w = valid ? wr : 0;
            const int qs = q ^ (w & 15);
            bf16x8 bfr = *(const bf16x8*)&B_lds[(((r << 6) + w) * 16 + qs) * 8];
            bfr = valid ? bfr : (bf16x8){0, 0, 0, 0, 0, 0, 0, 0};
            #pragma unroll
            for (int fm = 0; fm < 2; ++fm)
                acc[fm][fn] = __builtin_amdgcn_mfma_f32_32x32x16_bf16(
                    Ac[fm], bfr, acc[fm][fn], 0, 0, 0);
        }
        __builtin_amdgcn_s_setprio(0);
        if (s + 3 < 32) {
            const unsigned short* p = Ag + ((s + 3) << 10) + lane * 8;
            Abuf[s % 3][0] = *(const bf16x8*)p;
            Abuf[s % 3][1] = *(const bf16x8*)(p + 512);
        }
    }

    // ---- epilogue: direct stores; partner px-block (d^16) merges in L2.
    // C/D 32x32: col = l31 (sp), row = (j&3) + 8*(j>>2) + 4*lh (co)
    const int yy = 2 * (ys * 4 + ol) + py;
    #pragma unroll
    for (int fm = 0; fm < 2; ++fm) {
        #pragma unroll
        for (int fn = 0; fn < 2; ++fn) {
            const int xx = 2 * (fn * 32 + l31) + px;
            #pragma unroll
            for (int j = 0; j < 16; ++j) {
                const int row = (j & 3) + 8 * (j >> 2) + 4 * lh;
                const int co = coh * 64 + fm * 32 + row;
                out[(((size_t)(bi * NCO + co)) << 14) + yy * 128 + xx] =
                    acc[fm][fn][j] + bv[co];
            }
        }
    }
}

// -------- fallback: flat Weff + direct-x kernel (round-1 proven) --------
__global__ void weff_flat_kernel(const float* __restrict__ W,
                                 unsigned short* __restrict__ Aw) {
    int idx = blockIdx.x * 256 + threadIdx.x;   // Aw[par][co][512]
    int par = idx >> 16;
    int co  = (idx >> 9) & 127;
    int k   = idx & 511;
    int tap = k >> 7, ci = k & 127;
    Aw[idx] = f32_to_bf16(weff_sum(W + (co * NCI + ci) * 9,
                                   par >> 1, par & 1, tap >> 1, tap & 1));
}

__global__ __launch_bounds__(256) void upconv_fb_kernel(
        const float* __restrict__ x, const unsigned short* __restrict__ Aw,
        const float* __restrict__ bv, float* __restrict__ out) {
    __shared__ __align__(16) unsigned short A_lds[128 * 32];
    __shared__ __align__(16) unsigned short B_lds[128 * 32];
    const int par = blockIdx.y, py = par >> 1, px = par & 1;
    const int s0 = blockIdx.x * 128;
    const int bimg = s0 >> 12;
    const int oy0 = (s0 >> 6) & 63;
    const int tid = threadIdx.x;
    const int lane = tid & 63, wave = tid >> 6;
    const int wm = wave >> 1, wn = wave & 1;
    const float* xb = x + bimg * (NCI * HIN * HIN);
    f32x4 acc[4][4];
    #pragma unroll
    for (int i = 0; i < 4; ++i)
        #pragma unroll
        for (int j = 0; j < 4; ++j)
            acc[i][j] = (f32x4){0.f, 0.f, 0.f, 0.f};
    for (int kt = 0; kt < 16; ++kt) {
        const int tap = kt >> 2, ci0 = (kt & 3) * 32;
        const int ty = tap >> 1, tx = tap & 1;
        #pragma unroll
        for (int i = 0; i < 2; ++i) {
            int c = i * 256 + tid;
            *(bf16x8*)(&A_lds[c * 8]) = *(const bf16x8*)(Aw +
                ((par * 128 + (c >> 2)) * 512 + kt * 32 + (c & 3) * 8));
        }
        #pragma unroll
        for (int i = 0; i < 2; ++i) {
            int tsk = i * 256 + tid;
            int n = tsk & 127, kg = tsk >> 7;
            int r = n >> 6, ox = n & 63;
            int row = oy0 + r - 1 + py + ty;
            int col = ox - 1 + px + tx;
            bool ok = (row >= 0) & (row < HIN) & (col >= 0) & (col < HIN);
            const float* xp = xb + (((ci0 + kg * 8) * HIN + row) * HIN + col);
            bf16x8 v;
            #pragma unroll
            for (int q = 0; q < 8; ++q) {
                float f = ok ? xp[q * (HIN * HIN)] : 0.f;
                v[q] = (short)f32_to_bf16(f);
            }
            *(bf16x8*)(&B_lds[n * 32 + kg * 8]) = v;
        }
        __syncthreads();
        const int seg = (lane >> 4) * 8, rl2 = lane & 15;
        bf16x8 af[4], bfr[4];
        #pragma unroll
        for (int f = 0; f < 4; ++f)
            af[f] = *(const bf16x8*)(&A_lds[(wm * 64 + f * 16 + rl2) * 32 + seg]);
        #pragma unroll
        for (int f = 0; f < 4; ++f)
            bfr[f] = *(const bf16x8*)(&B_lds[(wn * 64 + f * 16 + rl2) * 32 + seg]);
        #pragma unroll
        for (int fm = 0; fm < 4; ++fm)
            #pragma unroll
            for (int fn = 0; fn < 4; ++fn)
                acc[fm][fn] = __builtin_amdgcn_mfma_f32_16x16x32_bf16(
                    af[fm], bfr[fn], acc[fm][fn], 0, 0, 0);
        __syncthreads();
    }
    #pragma unroll
    for (int fm = 0; fm < 4; ++fm) {
        const int co_b = wm * 64 + fm * 16 + (lane >> 4) * 4;
        float bias4[4];
        #pragma unroll
        for (int j = 0; j < 4; ++j) bias4[j] = bv[co_b + j];
        #pragma unroll
        for (int fn = 0; fn < 4; ++fn) {
            int n = wn * 64 + fn * 16 + (lane & 15);
            int s = s0 + n;
            int ox = s & 63, oy = (s >> 6) & 63, bi2 = s >> 12;
            int yy = 2 * oy + py, xx = 2 * ox + px;
            float* op = out + ((size_t)bi2 * 128 * 128 * 128) + (size_t)yy * 128 + xx;
            #pragma unroll
            for (int j = 0; j < 4; ++j)
                op[(size_t)(co_b + j) * (128 * 128)] = acc[fm][fn][j] + bias4[j];
        }
    }
}

extern "C" void kernel_launch(void* const* d_in, const int* in_sizes, int n_in,
                              void* d_out, int out_size, void* d_ws, size_t ws_size,
                              hipStream_t stream) {
    const float* x  = (const float*)d_in[0];
    const float* W  = (const float*)d_in[1];
    const float* bv = (const float*)d_in[2];
    float* out = (float*)d_out;
    unsigned short* Aw = (unsigned short*)d_ws;               // 512 KB
    const size_t aw_bytes = (size_t)4 * 2 * 32 * 2 * 512 * sizeof(unsigned short);

    if (ws_size >= aw_bytes) {
        weff9_kernel<<<1024, 256, 0, stream>>>(W, Aw);
        upconv19_kernel<<<1024, 256, 0, stream>>>(x, Aw, bv, out);
    } else {
        weff_flat_kernel<<<1024, 256, 0, stream>>>(W, Aw);
        upconv_fb_kernel<<<dim3(256, 4), 256, 0, stream>>>(x, Aw, bv, out);
    }
}

// Round 19
// 41.154 us; speedup vs baseline: 1.2896x; 1.2896x over previous
//
#include <hip/hip_runtime.h>
#include <stdint.h>

typedef short bf16x8 __attribute__((ext_vector_type(8)));
typedef float f32x4 __attribute__((ext_vector_type(4)));
typedef float f32x16 __attribute__((ext_vector_type(16)));

#define NCI 128
#define NCO 128
#define HIN 64
#define NB  8

__device__ __forceinline__ unsigned short f32_to_bf16(float f) {
    union { float f; uint32_t u; } v; v.f = f;
    return (unsigned short)((v.u + 0x7FFFu + ((v.u >> 16) & 1u)) >> 16);
}

__device__ __forceinline__ void gl_lds16(const void* g, void* l) {
    __builtin_amdgcn_global_load_lds(
        (const __attribute__((address_space(1))) unsigned int*)g,
        (__attribute__((address_space(3))) unsigned int*)l, 16, 0, 0);
}

// Effective 2x2-tap weight for parity (py,px), tap (ty,tx)
__device__ __forceinline__ float weff_sum(const float* wp, int py, int px, int ty, int tx) {
    float s = 0.f;
    #pragma unroll
    for (int ky = 0; ky < 3; ++ky) {
        bool iy = (py == 0) ? (ty == 0 ? (ky == 0) : (ky >= 1))
                            : (ty == 0 ? (ky <= 1) : (ky == 2));
        if (!iy) continue;
        #pragma unroll
        for (int kx = 0; kx < 3; ++kx) {
            bool ix = (px == 0) ? (tx == 0 ? (kx == 0) : (kx >= 1))
                                : (tx == 0 ? (kx <= 1) : (kx == 2));
            if (ix) s += wp[ky * 3 + kx];
        }
    }
    return s;
}

// ---- fused prologue ----
// blocks [0,1024): Weff -> Aw9 (1KB wave-line frags for 32x32x16):
//   offset = (((par*2+coh)*32 + s)*1024) + fm*512 + lane*8 + e
//   content = Weff[par][co = coh*64 + fm*32 + (lane&31)][k = s*16 + (lane>>5)*8 + e]
// blocks [1024,1552): x -> xq [8][4 g][66 hp][64 w][32 ci] bf16 (row halo only).
__global__ __launch_bounds__(256) void prep_kernel(
        const float* __restrict__ W, const float* __restrict__ x,
        unsigned short* __restrict__ Aw9, unsigned short* __restrict__ xq) {
    if (blockIdx.x < 1024) {
        int idx = blockIdx.x * 256 + threadIdx.x;     // 262144 total
        int e   = idx & 7;
        int l   = (idx >> 3) & 63;
        int fm  = (idx >> 9) & 1;
        int s   = (idx >> 10) & 31;
        int coh = (idx >> 15) & 1;
        int par = idx >> 16;
        int co = coh * 64 + fm * 32 + (l & 31);
        int k  = s * 16 + (l >> 5) * 8 + e;
        int tap = k >> 7, ci = k & 127;
        Aw9[idx] = f32_to_bf16(weff_sum(W + (co * NCI + ci) * 9,
                                        par >> 1, par & 1, tap >> 1, tap & 1));
    } else {
        const int bb = blockIdx.x - 1024;             // 528 blocks (8 b x 66 hp)
        const int b = bb / 66, hp = bb % 66;
        const int t = threadIdx.x;
        if (hp == 0 || hp == 65) {                    // zero halo rows, all 4 g
            bf16x8 z = (bf16x8){0, 0, 0, 0, 0, 0, 0, 0};
            for (int i = t; i < 1024; i += 256) {     // 4g x 64w x 4q
                int g = i >> 8, rem = i & 255;
                int w = rem >> 2, q = rem & 3;
                *(bf16x8*)(xq + (((((size_t)(b * 4 + g)) * 66 + hp) * 64 + w) << 5) + q * 8) = z;
            }
            return;
        }
        const int h = hp - 1;
        const int w = t & 63, g = t >> 6;
        const float* src = x + ((size_t)(b * NCI + g * 32) * (HIN * HIN)) + h * HIN + w;
        unsigned short* dst = xq + (((((size_t)(b * 4 + g)) * 66 + hp) * 64 + w) << 5);
        #pragma unroll
        for (int q = 0; q < 4; ++q) {
            bf16x8 v;
            #pragma unroll
            for (int j = 0; j < 8; ++j)
                v[j] = (short)f32_to_bf16(src[(size_t)(q * 8 + j) * (HIN * HIN)]);
            *(bf16x8*)(dst + q * 8) = v;
        }
    }
}

// Main GEMM (best known, round 16): B-only LDS (5 rows x 64 cols x 256B =
// 80 KB -> 2 blocks/CU, cross-block stage/compute overlap). A streams L2->reg
// 3-deep (1KB wave-lines). Block = (bi, py, px, coh, ys strip of 4 oy);
// 256 thr = 4 waves (ol = oy row); wave = 64co x 64sp, 32 steps x
// {2 A-reads(global), 2 B-reads(LDS, halo-select), 4 MFMA 32x32x16}.
__global__ __launch_bounds__(256, 2) void upconv17_kernel(
        const unsigned short* __restrict__ xq, const unsigned short* __restrict__ Aw9,
        const float* __restrict__ bv, float* __restrict__ out) {
    __shared__ __align__(16) unsigned short B_lds[40960];   // 81920 B exactly
    const int d = blockIdx.x;                 // 1024 blocks
    const int bi  = d & 7;                    // XCD-local image
    const int py  = (d >> 3) & 1;
    const int px  = (d >> 4) & 1;             // partner d^16 on same XCD
    const int coh = (d >> 5) & 1;
    const int ys  = d >> 6;                   // 0..15
    const int tid = threadIdx.x, lane = tid & 63, ol = tid >> 6;
    const int l31 = lane & 31, lh = lane >> 5;
    const int par = py * 2 + px;

    // ---- stage B window: 5120 x 16B; u -> (cell = u>>4, qs = u&15),
    //      cell = r*64 + w; source chunk q = qs ^ (w&15)  (rule #21) ----
    #pragma unroll
    for (int i = 0; i < 20; ++i) {
        const int u = i * 256 + tid;
        const int qs = u & 15, cell = u >> 4;
        const int r = cell >> 6, w = cell & 63;
        const int q = qs ^ (w & 15);
        const int hp = ys * 4 + py + r;       // 0..65 (row halo in xq)
        const unsigned short* gb = xq +
            (((((size_t)(bi * 4 + (q >> 2))) * 66 + hp) * 64 + w) << 5) + (q & 3) * 8;
        gl_lds16(gb, &B_lds[u * 8]);
    }

    const unsigned short* Ag = Aw9 + (((size_t)(par * 2 + coh)) << 15);
    bf16x8 Abuf[3][2];
    auto loadA = [&](bf16x8* Ad, int s) {
        const unsigned short* p = Ag + (s << 10) + lane * 8;
        Ad[0] = *(const bf16x8*)p;
        Ad[1] = *(const bf16x8*)(p + 512);
    };
    loadA(Abuf[0], 0);
    loadA(Abuf[1], 1);
    loadA(Abuf[2], 2);
    asm volatile("s_waitcnt vmcnt(0)" ::: "memory");
    __builtin_amdgcn_s_barrier();

    f32x16 acc[2][2];
    #pragma unroll
    for (int i = 0; i < 2; ++i)
        #pragma unroll
        for (int j = 0; j < 2; ++j)
            #pragma unroll
            for (int q = 0; q < 16; ++q)
                acc[i][j][q] = 0.f;

    #pragma unroll
    for (int s = 0; s < 32; ++s) {            // fully unrolled: s%3 static
        bf16x8* Ac = Abuf[s % 3];
        const int ty = s >> 4, tx = (s >> 3) & 1;
        const int q = (s & 7) * 2 + lh;
        const int r = ol + ty;                // 0..4
        __builtin_amdgcn_s_setprio(1);
        #pragma unroll
        for (int fn = 0; fn < 2; ++fn) {
            const int wr = fn * 32 + l31 + px + tx - 1;
            const bool valid = (unsigned)wr < 64u;
            const int w = valid ? wr : 0;
            const int qs = q ^ (w & 15);
            bf16x8 bfr = *(const bf16x8*)&B_lds[(((r << 6) + w) * 16 + qs) * 8];
            bfr = valid ? bfr : (bf16x8){0, 0, 0, 0, 0, 0, 0, 0};
            #pragma unroll
            for (int fm = 0; fm < 2; ++fm)
                acc[fm][fn] = __builtin_amdgcn_mfma_f32_32x32x16_bf16(
                    Ac[fm], bfr, acc[fm][fn], 0, 0, 0);
        }
        __builtin_amdgcn_s_setprio(0);
        if (s + 3 < 32) loadA(Abuf[s % 3], s + 3);
    }

    // ---- epilogue: direct stores; partner px-block merges in L2.
    // C/D 32x32: col = l31 (sp), row = (j&3) + 8*(j>>2) + 4*lh (co)
    const int yy = 2 * (ys * 4 + ol) + py;
    #pragma unroll
    for (int fm = 0; fm < 2; ++fm) {
        #pragma unroll
        for (int fn = 0; fn < 2; ++fn) {
            const int xx = 2 * (fn * 32 + l31) + px;
            #pragma unroll
            for (int j = 0; j < 16; ++j) {
                const int row = (j & 3) + 8 * (j >> 2) + 4 * lh;
                const int co = coh * 64 + fm * 32 + row;
                out[(((size_t)(bi * NCO + co)) << 14) + yy * 128 + xx] =
                    acc[fm][fn][j] + bv[co];
            }
        }
    }
}

// -------- fallback: flat Weff + direct-x kernel (round-1 proven) --------
__global__ void weff_flat_kernel(const float* __restrict__ W,
                                 unsigned short* __restrict__ Aw) {
    int idx = blockIdx.x * 256 + threadIdx.x;   // Aw[par][co][512]
    int par = idx >> 16;
    int co  = (idx >> 9) & 127;
    int k   = idx & 511;
    int tap = k >> 7, ci = k & 127;
    Aw[idx] = f32_to_bf16(weff_sum(W + (co * NCI + ci) * 9,
                                   par >> 1, par & 1, tap >> 1, tap & 1));
}

__global__ __launch_bounds__(256) void upconv_fb_kernel(
        const float* __restrict__ x, const unsigned short* __restrict__ Aw,
        const float* __restrict__ bv, float* __restrict__ out) {
    __shared__ __align__(16) unsigned short A_lds[128 * 32];
    __shared__ __align__(16) unsigned short B_lds[128 * 32];
    const int par = blockIdx.y, py = par >> 1, px = par & 1;
    const int s0 = blockIdx.x * 128;
    const int bimg = s0 >> 12;
    const int oy0 = (s0 >> 6) & 63;
    const int tid = threadIdx.x;
    const int lane = tid & 63, wave = tid >> 6;
    const int wm = wave >> 1, wn = wave & 1;
    const float* xb = x + bimg * (NCI * HIN * HIN);
    f32x4 acc[4][4];
    #pragma unroll
    for (int i = 0; i < 4; ++i)
        #pragma unroll
        for (int j = 0; j < 4; ++j)
            acc[i][j] = (f32x4){0.f, 0.f, 0.f, 0.f};
    for (int kt = 0; kt < 16; ++kt) {
        const int tap = kt >> 2, ci0 = (kt & 3) * 32;
        const int ty = tap >> 1, tx = tap & 1;
        #pragma unroll
        for (int i = 0; i < 2; ++i) {
            int c = i * 256 + tid;
            *(bf16x8*)(&A_lds[c * 8]) = *(const bf16x8*)(Aw +
                ((par * 128 + (c >> 2)) * 512 + kt * 32 + (c & 3) * 8));
        }
        #pragma unroll
        for (int i = 0; i < 2; ++i) {
            int tsk = i * 256 + tid;
            int n = tsk & 127, kg = tsk >> 7;
            int r = n >> 6, ox = n & 63;
            int row = oy0 + r - 1 + py + ty;
            int col = ox - 1 + px + tx;
            bool ok = (row >= 0) & (row < HIN) & (col >= 0) & (col < HIN);
            const float* xp = xb + (((ci0 + kg * 8) * HIN + row) * HIN + col);
            bf16x8 v;
            #pragma unroll
            for (int q = 0; q < 8; ++q) {
                float f = ok ? xp[q * (HIN * HIN)] : 0.f;
                v[q] = (short)f32_to_bf16(f);
            }
            *(bf16x8*)(&B_lds[n * 32 + kg * 8]) = v;
        }
        __syncthreads();
        const int seg = (lane >> 4) * 8, rl2 = lane & 15;
        bf16x8 af[4], bfr[4];
        #pragma unroll
        for (int f = 0; f < 4; ++f)
            af[f] = *(const bf16x8*)(&A_lds[(wm * 64 + f * 16 + rl2) * 32 + seg]);
        #pragma unroll
        for (int f = 0; f < 4; ++f)
            bfr[f] = *(const bf16x8*)(&B_lds[(wn * 64 + f * 16 + rl2) * 32 + seg]);
        #pragma unroll
        for (int fm = 0; fm < 4; ++fm)
            #pragma unroll
            for (int fn = 0; fn < 4; ++fn)
                acc[fm][fn] = __builtin_amdgcn_mfma_f32_16x16x32_bf16(
                    af[fm], bfr[fn], acc[fm][fn], 0, 0, 0);
        __syncthreads();
    }
    #pragma unroll
    for (int fm = 0; fm < 4; ++fm) {
        const int co_b = wm * 64 + fm * 16 + (lane >> 4) * 4;
        float bias4[4];
        #pragma unroll
        for (int j = 0; j < 4; ++j) bias4[j] = bv[co_b + j];
        #pragma unroll
        for (int fn = 0; fn < 4; ++fn) {
            int n = wn * 64 + fn * 16 + (lane & 15);
            int s = s0 + n;
            int ox = s & 63, oy = (s >> 6) & 63, bi2 = s >> 12;
            int yy = 2 * oy + py, xx = 2 * ox + px;
            float* op = out + ((size_t)bi2 * 128 * 128 * 128) + (size_t)yy * 128 + xx;
            #pragma unroll
            for (int j = 0; j < 4; ++j)
                op[(size_t)(co_b + j) * (128 * 128)] = acc[fm][fn][j] + bias4[j];
        }
    }
}

extern "C" void kernel_launch(void* const* d_in, const int* in_sizes, int n_in,
                              void* d_out, int out_size, void* d_ws, size_t ws_size,
                              hipStream_t stream) {
    const float* x  = (const float*)d_in[0];
    const float* W  = (const float*)d_in[1];
    const float* bv = (const float*)d_in[2];
    float* out = (float*)d_out;
    unsigned short* Aw = (unsigned short*)d_ws;               // 512 KB
    const size_t aw_bytes = (size_t)4 * 2 * 32 * 2 * 512 * sizeof(unsigned short);
    const size_t xq_bytes = (size_t)NB * 4 * 66 * 64 * 32 * sizeof(unsigned short);

    if (ws_size >= aw_bytes + xq_bytes) {
        unsigned short* xq = (unsigned short*)((char*)d_ws + aw_bytes);
        prep_kernel<<<1024 + 528, 256, 0, stream>>>(W, x, Aw, xq);
        upconv17_kernel<<<1024, 256, 0, stream>>>(xq, Aw, bv, out);
    } else {
        weff_flat_kernel<<<1024, 256, 0, stream>>>(W, Aw);
        upconv_fb_kernel<<<dim3(256, 4), 256, 0, stream>>>(x, Aw, bv, out);
    }
}